// Round 5
// baseline (335.280 us; speedup 1.0000x reference)
//
#include <hip/hip_runtime.h>
#include <hip/hip_bf16.h>
#include <math.h>

#define NPART 8

typedef __attribute__((ext_vector_type(8))) short bf16x8;
typedef __attribute__((ext_vector_type(4))) float f32x4;

__device__ __forceinline__ float lrelu(float v) { return fmaxf(v, 0.2f * v); }

// monotone float <-> uint encoding for atomicMax on signed floats
__device__ __forceinline__ unsigned fenc(float f) {
    unsigned u = __float_as_uint(f);
    return (u & 0x80000000u) ? ~u : (u | 0x80000000u);
}
__device__ __forceinline__ float fdec(unsigned u) {
    return __uint_as_float((u & 0x80000000u) ? (u & 0x7FFFFFFFu) : ~u);
}
__device__ __forceinline__ unsigned short f2bf(float f) {
    union { __hip_bfloat16 b; unsigned short u; } cv;
    cv.b = __float2bfloat16(f);
    return cv.u;
}

// ---------------- CSR build (sort edges by dst), XCD-partitioned, deg padded to x4 ----------------

__global__ void deg_init(int* deg, int N, unsigned* gmax) {
    int i = blockIdx.x * blockDim.x + threadIdx.x;
    if (i < N) deg[i] = 1;                    // self-loop
    if (i < 12) gmax[i] = fenc(-1e30f);       // per-layer per-head global max seeds
}

__global__ void deg_count_part(const int* __restrict__ ei, int E, int N, int* deg, int pn) {
    int part = blockIdx.x & (NPART - 1);
    int nb = gridDim.x >> 3;
    int chunk = blockIdx.x >> 3;
    int stride = nb * blockDim.x;
    int lo = part * pn, hi = min(lo + pn, N);
    for (int i = chunk * blockDim.x + threadIdx.x; i < E; i += stride) {
        int d = ei[E + i];
        if (d >= lo && d < hi) atomicAdd(&deg[d], 1);
    }
}

__global__ void scan_partial(const int* __restrict__ deg, int N, int* bsum) {
    __shared__ int sm[256];
    int t = threadIdx.x;
    int i = blockIdx.x * 256 + t;
    int v = (i < N) ? ((deg[i] + 3) & ~3) : 0;     // padded degree
    sm[t] = v; __syncthreads();
    for (int o = 1; o < 256; o <<= 1) {
        int u = (t >= o) ? sm[t - o] : 0;
        __syncthreads();
        sm[t] += u;
        __syncthreads();
    }
    if (t == 255) bsum[blockIdx.x] = sm[255];
}

__global__ void scan_bsums(int* bsum, int nb) {
    __shared__ int sm[256];
    int t = threadIdx.x;
    int v = (t < nb) ? bsum[t] : 0;
    sm[t] = v; __syncthreads();
    for (int o = 1; o < 256; o <<= 1) {
        int u = (t >= o) ? sm[t - o] : 0;
        __syncthreads();
        sm[t] += u;
        __syncthreads();
    }
    if (t < nb) bsum[t] = sm[t] - v;          // exclusive
}

__global__ void scan_final(const int* __restrict__ deg, const int* __restrict__ bsum,
                           int N, int* offs, int* cursor) {
    __shared__ int sm[256];
    int t = threadIdx.x;
    int i = blockIdx.x * 256 + t;
    int v = (i < N) ? ((deg[i] + 3) & ~3) : 0;     // padded degree
    sm[t] = v; __syncthreads();
    for (int o = 1; o < 256; o <<= 1) {
        int u = (t >= o) ? sm[t - o] : 0;
        __syncthreads();
        sm[t] += u;
        __syncthreads();
    }
    int incl = sm[t] + bsum[blockIdx.x];
    if (i < N) { offs[i + 1] = incl; cursor[i] = incl - v; }
    if (i == 0) offs[0] = 0;
}

__global__ void scatter_part(const int* __restrict__ ei, int E, int N,
                             int* cursor, int* srcs, int pn) {
    int part = blockIdx.x & (NPART - 1);
    int nb = gridDim.x >> 3;
    int chunk = blockIdx.x >> 3;
    int stride = nb * blockDim.x;
    int lo = part * pn, hi = min(lo + pn, N);
    for (int i = chunk * blockDim.x + threadIdx.x; i < E; i += stride) {
        int d = ei[E + i];
        if (d >= lo && d < hi) {
            int pos = atomicAdd(&cursor[d], 1);
            srcs[pos] = ei[i];
        }
    }
    for (int i = chunk * blockDim.x + threadIdx.x + lo; i < hi; i += stride) {
        int pos = atomicAdd(&cursor[i], 1);
        srcs[pos] = i;                         // self-loop
    }
}

__global__ void pad_fill(const int* __restrict__ deg, const int* __restrict__ offs,
                         int* srcs, int N) {
    int n = blockIdx.x * blockDim.x + threadIdx.x;
    if (n >= N) return;
    int d = deg[n];
    int beg = offs[n], end = offs[n + 1];
    int s0 = srcs[beg] | 0x80000000;           // sentinel: dup first neighbor, flagged
    for (int k = beg + d; k < end; k++) srcs[k] = s0;
}

// ---------------- input conversions ----------------

__global__ void conv_x(const float* __restrict__ x, unsigned short* __restrict__ xb, int n4) {
    int i = blockIdx.x * blockDim.x + threadIdx.x;
    if (i >= n4) return;
    float4 v = *(const float4*)&x[i * 4];
    ushort4 o;
    o.x = f2bf(v.x); o.y = f2bf(v.y); o.z = f2bf(v.z); o.w = f2bf(v.w);
    *(ushort4*)&xb[i * 4] = o;
}

__global__ void conv_w(const float* __restrict__ W1, const float* __restrict__ W2,
                       const float* __restrict__ W3, unsigned short* __restrict__ Wt1,
                       unsigned short* __restrict__ Wt2, unsigned short* __restrict__ Wt3) {
    const float* W = (blockIdx.x == 0) ? W1 : (blockIdx.x == 1) ? W2 : W3;
    unsigned short* Wt = (blockIdx.x == 0) ? Wt1 : (blockIdx.x == 1) ? Wt2 : Wt3;
    for (int i = threadIdx.x; i < 128 * 128; i += blockDim.x) {
        int k = i >> 7, c = i & 127;
        Wt[c * 128 + k] = f2bf(W[i]);          // transpose: Wt[col][k]
    }
}

// ------- MFMA GEMM + fused logits + global-max: h = X@W (bf16), per-(node,head) as/ad -------
// per wave: 16 rows x 128 cols, K=128. A from xb rows, B from Wt cols (both bf16, 16B/lane frags)

template <int H>
__global__ __launch_bounds__(256) void gemm_mfma(const unsigned short* __restrict__ xb,
                                                 const unsigned short* __restrict__ Wt,
                                                 const float* __restrict__ a_s,
                                                 const float* __restrict__ a_d,
                                                 unsigned short* __restrict__ hb,
                                                 float* __restrict__ asb,
                                                 float* __restrict__ adb,
                                                 unsigned* __restrict__ gmax, int N) {
    constexpr int HH = (H == 4) ? 4 : 1;
    __shared__ float smax[4][HH];
    int t = threadIdx.x;
    int wave = t >> 6, lane = t & 63;
    int lrow = lane & 15;                       // A-row / D-col index
    int kg = lane >> 4;                         // k-group (8 contiguous k)
    int row0 = blockIdx.x * 64 + wave * 16;
    int arow = min(row0 + lrow, N - 1);         // clamp: OOB rows duplicate row N-1 (harmless)
    const bf16x8* ap = (const bf16x8*)(xb + (size_t)arow * 128 + kg * 8);

    f32x4 acc[8];
#pragma unroll
    for (int ct = 0; ct < 8; ct++) acc[ct] = (f32x4)0.f;

#pragma unroll
    for (int kk = 0; kk < 4; kk++) {
        bf16x8 a = ap[kk * 4];                  // advance 32 bf16 per k-step
#pragma unroll
        for (int ct = 0; ct < 8; ct++) {
            const bf16x8* bp = (const bf16x8*)(Wt + (size_t)(ct * 16 + lrow) * 128 + kk * 32 + kg * 8);
            acc[ct] = __builtin_amdgcn_mfma_f32_16x16x32_bf16(a, *bp, acc[ct], 0, 0, 0);
        }
    }

    // D layout: row = kg*4 + reg, col = ct*16 + lrow  [m89-verified]
    int orow = row0 + kg * 4;
    // store bf16 h
#pragma unroll
    for (int reg = 0; reg < 4; reg++) {
        int r = orow + reg;
        if (r < N) {
#pragma unroll
            for (int ct = 0; ct < 8; ct++)
                hb[(size_t)r * 128 + ct * 16 + lrow] = f2bf(acc[ct][reg]);
        }
    }
    // logits: ps/pd[reg][head], a_* flat over 128 cols
    float ps[4][HH], pd[4][HH];
#pragma unroll
    for (int reg = 0; reg < 4; reg++)
#pragma unroll
        for (int hd = 0; hd < HH; hd++) { ps[reg][hd] = 0.f; pd[reg][hd] = 0.f; }
#pragma unroll
    for (int ct = 0; ct < 8; ct++) {
        int hd = (H == 4) ? (ct >> 1) : 0;
        float asv = a_s[ct * 16 + lrow];
        float adv = a_d[ct * 16 + lrow];
#pragma unroll
        for (int reg = 0; reg < 4; reg++) {
            ps[reg][hd] += acc[ct][reg] * asv;
            pd[reg][hd] += acc[ct][reg] * adv;
        }
    }
    // butterfly-sum the 16 col-lanes
    for (int o = 1; o < 16; o <<= 1) {
#pragma unroll
        for (int reg = 0; reg < 4; reg++)
#pragma unroll
            for (int hd = 0; hd < HH; hd++) {
                ps[reg][hd] += __shfl_xor(ps[reg][hd], o);
                pd[reg][hd] += __shfl_xor(pd[reg][hd], o);
            }
    }
    if (lrow < HH) {
        int hd = lrow;
#pragma unroll
        for (int reg = 0; reg < 4; reg++) {
            int r = orow + reg;
            if (r < N) {
                asb[(size_t)r * H + hd] = ps[reg][hd];
                adb[(size_t)r * H + hd] = pd[reg][hd];
            }
        }
    }
    // wave max over rows, then block reduce, then 1 atomic per (block, head)
    float wm[HH];
#pragma unroll
    for (int hd = 0; hd < HH; hd++) {
        float m = fmaxf(fmaxf(ps[0][hd], ps[1][hd]), fmaxf(ps[2][hd], ps[3][hd]));
        m = fmaxf(m, __shfl_xor(m, 16));
        m = fmaxf(m, __shfl_xor(m, 32));
        wm[hd] = m;
    }
    if (lane == 0)
#pragma unroll
        for (int hd = 0; hd < HH; hd++) smax[wave][hd] = wm[hd];
    __syncthreads();
    if (t < HH) {
        float m = fmaxf(fmaxf(smax[0][t], smax[1][t]), fmaxf(smax[2][t], smax[3][t]));
        atomicMax(&gmax[t], fenc(m));
    }
}

// ------- aggregation: wave per dst node, padded CSR (x4, sentinel sign-bit), 32-bit addressing -------

template <int H, bool RELU, bool OUTBF>
__global__ __launch_bounds__(256) void aggregate6(const unsigned short* __restrict__ hb,
                                                  const int* __restrict__ offs,
                                                  const int* __restrict__ srcs,
                                                  const float* __restrict__ asb,
                                                  const float* __restrict__ adb,
                                                  const unsigned* __restrict__ gmax,
                                                  const float* __restrict__ bias,
                                                  void* __restrict__ outv, int N) {
    int n = (blockIdx.x * 256 + threadIdx.x) >> 6;   // wave id = node
    if (n >= N) return;
    unsigned lane = threadIdx.x & 63;
    unsigned ht = (H == 4) ? (lane >> 4) : 0;
    float adn = adb[(unsigned)n * H + ht];
    float m = lrelu(fdec(gmax[ht]) + adn);            // global-bound stabilizer
    int beg = offs[n], end = offs[n + 1];             // beg 16B-aligned, length % 4 == 0
    const unsigned* hb32 = (const unsigned*)hb;
    const int4* sp = (const int4*)(srcs + beg);
    int nb = (end - beg) >> 2;
    float accx = 0.f, accy = 0.f, den = 0.f;
    for (int b = 0; b < nb; b++) {
        int4 sv = sp[b];
        unsigned s0 = sv.x & 0x7FFFFFFF, s1 = sv.y & 0x7FFFFFFF;
        unsigned s2 = sv.z & 0x7FFFFFFF, s3 = sv.w & 0x7FFFFFFF;
        unsigned u0 = hb32[s0 * 64u + lane];
        unsigned u1 = hb32[s1 * 64u + lane];
        unsigned u2 = hb32[s2 * 64u + lane];
        unsigned u3 = hb32[s3 * 64u + lane];
        float e0 = asb[s0 * H + ht], e1 = asb[s1 * H + ht];
        float e2 = asb[s2 * H + ht], e3 = asb[s3 * H + ht];
        float p0 = __expf(lrelu(e0 + adn) - m);
        float p1 = __expf(lrelu(e1 + adn) - m);
        float p2 = __expf(lrelu(e2 + adn) - m);
        float p3 = __expf(lrelu(e3 + adn) - m);
        p0 = (sv.x < 0) ? 0.f : p0;
        p1 = (sv.y < 0) ? 0.f : p1;
        p2 = (sv.z < 0) ? 0.f : p2;
        p3 = (sv.w < 0) ? 0.f : p3;
        accx += p0 * __uint_as_float(u0 << 16);
        accy += p0 * __uint_as_float(u0 & 0xFFFF0000u);
        accx += p1 * __uint_as_float(u1 << 16);
        accy += p1 * __uint_as_float(u1 & 0xFFFF0000u);
        accx += p2 * __uint_as_float(u2 << 16);
        accy += p2 * __uint_as_float(u2 & 0xFFFF0000u);
        accx += p3 * __uint_as_float(u3 << 16);
        accy += p3 * __uint_as_float(u3 & 0xFFFF0000u);
        den += p0 + p1 + p2 + p3;
    }
    float inv = 1.f / (den + 1e-16f);
    unsigned c = lane * 2;
    float2 bv = *(const float2*)&bias[c];
    float o0 = accx * inv + bv.x;
    float o1 = accy * inv + bv.y;
    if (RELU) { o0 = fmaxf(o0, 0.f); o1 = fmaxf(o1, 0.f); }
    if (OUTBF) {
        ushort2 o; o.x = f2bf(o0); o.y = f2bf(o1);
        *(ushort2*)&((unsigned short*)outv)[(size_t)n * 128 + c] = o;
    } else {
        float2 o; o.x = o0; o.y = o1;
        *(float2*)&((float*)outv)[(size_t)n * 128 + c] = o;
    }
}

// ---------------- launch ----------------

extern "C" void kernel_launch(void* const* d_in, const int* in_sizes, int n_in,
                              void* d_out, int out_size, void* d_ws, size_t ws_size,
                              hipStream_t stream) {
    const float* x   = (const float*)d_in[0];
    const int*   ei  = (const int*)d_in[1];
    const float* W1  = (const float*)d_in[2];
    const float* as1 = (const float*)d_in[3];
    const float* ad1 = (const float*)d_in[4];
    const float* b1  = (const float*)d_in[5];
    const float* W2  = (const float*)d_in[6];
    const float* as2 = (const float*)d_in[7];
    const float* ad2 = (const float*)d_in[8];
    const float* b2  = (const float*)d_in[9];
    const float* W3  = (const float*)d_in[10];
    const float* as3 = (const float*)d_in[11];
    const float* ad3 = (const float*)d_in[12];
    const float* b3  = (const float*)d_in[13];

    const int N = in_sizes[0] / 128;
    const int E = in_sizes[1] / 2;
    const int NB = (N + 255) / 256;
    const int PN = (N + NPART - 1) / NPART;

    char* w = (char*)d_ws;
    size_t woff = 0;
    auto alloc = [&](size_t bytes) -> void* {
        void* p = w + woff;
        woff = (woff + bytes + 255) & ~(size_t)255;
        return p;
    };
    int*      deg    = (int*)alloc((size_t)(N + 1) * 4);
    int*      offs   = (int*)alloc((size_t)(N + 1) * 4);
    int*      cursor = (int*)alloc((size_t)(N + 1) * 4);
    int*      bsum   = (int*)alloc((size_t)NB * 4);
    int*      srcs   = (int*)alloc(((size_t)E + 4 * (size_t)N) * 4);   // padded CSR
    float*    asb    = (float*)alloc((size_t)N * 4 * 4);
    float*    adb    = (float*)alloc((size_t)N * 4 * 4);
    unsigned* gmax   = (unsigned*)alloc(16 * 4);
    unsigned short* hb  = (unsigned short*)alloc((size_t)N * 128 * 2);
    unsigned short* xb  = (unsigned short*)alloc((size_t)N * 128 * 2);
    unsigned short* Wt1 = (unsigned short*)alloc(128 * 128 * 2);
    unsigned short* Wt2 = (unsigned short*)alloc(128 * 128 * 2);
    unsigned short* Wt3 = (unsigned short*)alloc(128 * 128 * 2);
    float* outf = (float*)d_out;

    // input conversions (independent of CSR)
    conv_x<<<(N * 128 / 4 + 255) / 256, 256, 0, stream>>>(x, xb, N * 128 / 4);
    conv_w<<<3, 256, 0, stream>>>(W1, W2, W3, Wt1, Wt2, Wt3);

    // CSR build (XCD-partitioned, padded)
    deg_init<<<(N + 255) / 256, 256, 0, stream>>>(deg, N, gmax);
    deg_count_part<<<2048, 256, 0, stream>>>(ei, E, N, deg, PN);
    scan_partial<<<NB, 256, 0, stream>>>(deg, N, bsum);
    scan_bsums<<<1, 256, 0, stream>>>(bsum, NB);
    scan_final<<<NB, 256, 0, stream>>>(deg, bsum, N, offs, cursor);
    scatter_part<<<2048, 256, 0, stream>>>(ei, E, N, cursor, srcs, PN);
    pad_fill<<<(N + 255) / 256, 256, 0, stream>>>(deg, offs, srcs, N);

    const int gb = (N + 63) / 64;
    const int ga = (N + 3) / 4;

    // Layer 1: xb -> hb -> xb (bf16, relu)
    gemm_mfma<4><<<gb, 256, 0, stream>>>(xb, Wt1, as1, ad1, hb, asb, adb, gmax + 0, N);
    aggregate6<4, true, true><<<ga, 256, 0, stream>>>(hb, offs, srcs, asb, adb, gmax + 0, b1, xb, N);

    // Layer 2: xb -> hb -> xb (bf16, relu)
    gemm_mfma<4><<<gb, 256, 0, stream>>>(xb, Wt2, as2, ad2, hb, asb, adb, gmax + 4, N);
    aggregate6<4, true, true><<<ga, 256, 0, stream>>>(hb, offs, srcs, asb, adb, gmax + 4, b2, xb, N);

    // Layer 3: xb -> hb -> d_out (fp32, H=1, no relu)
    gemm_mfma<1><<<gb, 256, 0, stream>>>(xb, Wt3, as3, ad3, hb, asb, adb, gmax + 8, N);
    aggregate6<1, false, false><<<ga, 256, 0, stream>>>(hb, offs, srcs, asb, adb, gmax + 8, b3, outf, N);
}

// Round 6
// 327.516 us; speedup vs baseline: 1.0237x; 1.0237x over previous
//
#include <hip/hip_runtime.h>
#include <hip/hip_bf16.h>
#include <math.h>

#define NPART 8

typedef __attribute__((ext_vector_type(8))) short bf16x8;
typedef __attribute__((ext_vector_type(4))) float f32x4;

__device__ __forceinline__ float lrelu(float v) { return fmaxf(v, 0.2f * v); }

__device__ __forceinline__ unsigned fenc(float f) {
    unsigned u = __float_as_uint(f);
    return (u & 0x80000000u) ? ~u : (u | 0x80000000u);
}
__device__ __forceinline__ float fdec(unsigned u) {
    return __uint_as_float((u & 0x80000000u) ? (u & 0x7FFFFFFFu) : ~u);
}
__device__ __forceinline__ unsigned short f2bf(float f) {
    union { __hip_bfloat16 b; unsigned short u; } cv;
    cv.b = __float2bfloat16(f);
    return cv.u;
}
__device__ __forceinline__ float bflo(unsigned u) { return __uint_as_float(u << 16); }
__device__ __forceinline__ float bfhi(unsigned u) { return __uint_as_float(u & 0xFFFF0000u); }

// ---------------- setup: conv x->bf16, W->Wt bf16, deg=1, gmax seed, dummy hb row ----------------

__global__ void setup(const float* __restrict__ x,
                      const float* __restrict__ W1, const float* __restrict__ W2,
                      const float* __restrict__ W3,
                      unsigned short* __restrict__ xb,
                      unsigned short* __restrict__ Wt1, unsigned short* __restrict__ Wt2,
                      unsigned short* __restrict__ Wt3,
                      int* __restrict__ deg, unsigned* __restrict__ gmax,
                      unsigned short* __restrict__ hb, int N) {
    int i = blockIdx.x * blockDim.x + threadIdx.x;
    int nx = N * 32;
    if (i < nx) {
        float4 v = ((const float4*)x)[i];
        ushort4 o;
        o.x = f2bf(v.x); o.y = f2bf(v.y); o.z = f2bf(v.z); o.w = f2bf(v.w);
        ((ushort4*)xb)[i] = o;
        if (i < N) deg[i] = 1;                               // self-loop
        if (i < 12) gmax[i] = fenc(-1e30f);
        if (i < 64) ((unsigned*)hb)[(size_t)N * 64 + i] = 0; // dummy row N = 0
        return;
    }
    int j = i - nx;
    if (j < 3 * 16384) {
        int mm = j >> 14, e = j & 16383;
        const float* W = (mm == 0) ? W1 : (mm == 1) ? W2 : W3;
        unsigned short* Wt = (mm == 0) ? Wt1 : (mm == 1) ? Wt2 : Wt3;
        int k = e >> 7, c = e & 127;
        Wt[c * 128 + k] = f2bf(W[e]);                        // Wt[col][k]
    }
}

// ---------------- CSR build (dst-sorted), XCD-partitioned, padded to x4 with dummy N ----------------

__global__ void deg_count_part(const int* __restrict__ ei, int E, int N, int* deg, int pn) {
    int part = blockIdx.x & (NPART - 1);
    int nb = gridDim.x >> 3;
    int chunk = blockIdx.x >> 3;
    int stride = nb * blockDim.x;
    int lo = part * pn, hi = min(lo + pn, N);
    for (int i = chunk * blockDim.x + threadIdx.x; i < E; i += stride) {
        int d = ei[E + i];
        if (d >= lo && d < hi) atomicAdd(&deg[d], 1);
    }
}

__global__ void scan_partial(const int* __restrict__ deg, int N, int* bsum) {
    __shared__ int sm[256];
    int t = threadIdx.x;
    int i = blockIdx.x * 256 + t;
    int v = (i < N) ? ((deg[i] + 3) & ~3) : 0;
    sm[t] = v; __syncthreads();
    for (int o = 1; o < 256; o <<= 1) {
        int u = (t >= o) ? sm[t - o] : 0;
        __syncthreads();
        sm[t] += u;
        __syncthreads();
    }
    if (t == 255) bsum[blockIdx.x] = sm[255];
}

__global__ void scan_bsums(int* bsum, int nb) {
    __shared__ int sm[256];
    int t = threadIdx.x;
    int v = (t < nb) ? bsum[t] : 0;
    sm[t] = v; __syncthreads();
    for (int o = 1; o < 256; o <<= 1) {
        int u = (t >= o) ? sm[t - o] : 0;
        __syncthreads();
        sm[t] += u;
        __syncthreads();
    }
    if (t < nb) bsum[t] = sm[t] - v;          // exclusive
}

// also writes self-loop at segment start and dummy pads (idx N) at segment tail
__global__ void scan_final(const int* __restrict__ deg, const int* __restrict__ bsum,
                           int N, int* offs, int* cursor, int* srcs) {
    __shared__ int sm[256];
    int t = threadIdx.x;
    int i = blockIdx.x * 256 + t;
    int dr = (i < N) ? deg[i] : 0;
    int v = (dr + 3) & ~3;
    sm[t] = v; __syncthreads();
    for (int o = 1; o < 256; o <<= 1) {
        int u = (t >= o) ? sm[t - o] : 0;
        __syncthreads();
        sm[t] += u;
        __syncthreads();
    }
    int incl = sm[t] + bsum[blockIdx.x];
    if (i < N) {
        int beg = incl - v;
        offs[i + 1] = incl;
        cursor[i] = beg + 1;                   // slot 0 = self-loop
        srcs[beg] = i;
        for (int k = beg + dr; k < incl; k++) srcs[k] = N;   // dummy pads
    }
    if (i == 0) offs[0] = 0;
}

__global__ void scatter_part(const int* __restrict__ ei, int E, int N,
                             int* cursor, int* srcs, int pn) {
    int part = blockIdx.x & (NPART - 1);
    int nb = gridDim.x >> 3;
    int chunk = blockIdx.x >> 3;
    int stride = nb * blockDim.x;
    int lo = part * pn, hi = min(lo + pn, N);
    for (int i = chunk * blockDim.x + threadIdx.x; i < E; i += stride) {
        int d = ei[E + i];
        if (d >= lo && d < hi) {
            int pos = atomicAdd(&cursor[d], 1);
            srcs[pos] = ei[i];
        }
    }
}

// ------- MFMA GEMM: h = X@W (bf16 out). per wave: 16 rows x 128 cols, K=128 -------

__global__ __launch_bounds__(256) void gemm_mfma(const unsigned short* __restrict__ xb,
                                                 const unsigned short* __restrict__ Wt,
                                                 unsigned short* __restrict__ hb, int N) {
    int t = threadIdx.x;
    int wave = t >> 6, lane = t & 63;
    int lrow = lane & 15;
    int kg = lane >> 4;
    int row0 = blockIdx.x * 64 + wave * 16;
    int arow = min(row0 + lrow, N - 1);
    const bf16x8* ap = (const bf16x8*)(xb + (size_t)arow * 128 + kg * 8);

    f32x4 acc[8];
#pragma unroll
    for (int ct = 0; ct < 8; ct++) acc[ct] = (f32x4)0.f;

#pragma unroll
    for (int kk = 0; kk < 4; kk++) {
        bf16x8 a = ap[kk * 4];
#pragma unroll
        for (int ct = 0; ct < 8; ct++) {
            const bf16x8* bp = (const bf16x8*)(Wt + (size_t)(ct * 16 + lrow) * 128 + kk * 32 + kg * 8);
            acc[ct] = __builtin_amdgcn_mfma_f32_16x16x32_bf16(a, *bp, acc[ct], 0, 0, 0);
        }
    }
    // D layout: row = kg*4 + reg, col = ct*16 + lrow
    int orow = row0 + kg * 4;
#pragma unroll
    for (int reg = 0; reg < 4; reg++) {
        int r = orow + reg;
        if (r < N) {
#pragma unroll
            for (int ct = 0; ct < 8; ct++)
                hb[(size_t)r * 128 + ct * 16 + lrow] = f2bf(acc[ct][reg]);
        }
    }
}

// ------- logits from bf16 h: as/ad per (node,head) + per-head global max -------
// wave handles 8 rows; lane covers 16 cols ((lane&7)*16)

template <int H>
__global__ __launch_bounds__(256) void logits_k(const unsigned short* __restrict__ hb,
                                                const float* __restrict__ a_s,
                                                const float* __restrict__ a_d,
                                                float* __restrict__ asb, float* __restrict__ adb,
                                                unsigned* __restrict__ gmax, int N) {
    __shared__ float sm[4][4];
    int t = threadIdx.x, wave = t >> 6, lane = t & 63;
    int row = (blockIdx.x * 4 + wave) * 8 + (lane >> 3);
    int rr = min(row, N - 1);
    int c0 = (lane & 7) * 16;
    const uint4* hp = (const uint4*)(hb + (size_t)rr * 128 + c0);
    uint4 h0 = hp[0], h1 = hp[1];
    unsigned uw[8] = {h0.x, h0.y, h0.z, h0.w, h1.x, h1.y, h1.z, h1.w};
    float hv[16];
#pragma unroll
    for (int q = 0; q < 8; q++) { hv[2 * q] = bflo(uw[q]); hv[2 * q + 1] = bfhi(uw[q]); }
    const float4* asp = (const float4*)(a_s + c0);
    const float4* adp = (const float4*)(a_d + c0);
    float s = 0.f, d = 0.f;
#pragma unroll
    for (int q = 0; q < 4; q++) {
        float4 a = asp[q], b = adp[q];
        s += hv[4 * q] * a.x + hv[4 * q + 1] * a.y + hv[4 * q + 2] * a.z + hv[4 * q + 3] * a.w;
        d += hv[4 * q] * b.x + hv[4 * q + 1] * b.y + hv[4 * q + 2] * b.z + hv[4 * q + 3] * b.w;
    }
    if (H == 4) {
        s += __shfl_xor(s, 1); d += __shfl_xor(d, 1);
    } else {
        for (int o = 1; o < 8; o <<= 1) { s += __shfl_xor(s, o); d += __shfl_xor(d, o); }
    }
    int head = (H == 4) ? ((lane & 7) >> 1) : 0;
    bool wr = (H == 4) ? ((lane & 1) == 0) : ((lane & 7) == 0);
    if (wr && row < N) {
        asb[(size_t)row * H + head] = s;
        adb[(size_t)row * H + head] = d;
    }
    float sv = (row < N) ? s : -1e30f;
    sv = fmaxf(sv, __shfl_xor(sv, 8));
    sv = fmaxf(sv, __shfl_xor(sv, 16));
    sv = fmaxf(sv, __shfl_xor(sv, 32));
    if (lane < 8 && !(lane & 1)) sm[wave][lane >> 1] = sv;
    __syncthreads();
    if (t < H) {
        float m = fmaxf(fmaxf(sm[0][t], sm[1][t]), fmaxf(sm[2][t], sm[3][t]));
        atomicMax(&gmax[t], fenc(m));
        if (blockIdx.x == 0) asb[(size_t)N * H + t] = -1e30f;   // dummy logit -> p=0
    }
}

// ------- aggregation: HALF-wave per dst node (32 lanes x 4ch), padded CSR, dummy-N slots -------

template <int H, bool RELU, bool OUTBF>
__global__ __launch_bounds__(256) void aggregate7(const unsigned short* __restrict__ hb,
                                                  const int* __restrict__ offs,
                                                  const int* __restrict__ srcs,
                                                  const float* __restrict__ asb,
                                                  const float* __restrict__ adb,
                                                  const unsigned* __restrict__ gmax,
                                                  const float* __restrict__ bias,
                                                  void* __restrict__ outv, int N) {
    int n = (blockIdx.x * 256 + threadIdx.x) >> 5;     // half-wave id = node
    if (n >= N) return;
    unsigned l = threadIdx.x & 31;
    unsigned ht = (H == 4) ? (l >> 3) : 0;
    float adn = adb[(unsigned)n * H + ht];
    float m = lrelu(fdec(gmax[ht]) + adn);
    int beg = offs[n];
    int nb = (offs[n + 1] - beg) >> 2;
    const uint2* hb64 = (const uint2*)hb;               // 8B per lane = 4 bf16
    const int4* sp = (const int4*)(srcs + beg);
    float a0 = 0.f, a1 = 0.f, a2 = 0.f, a3 = 0.f, den = 0.f;
    for (int b = 0; b < nb; b++) {
        int4 sv = sp[b];
        unsigned s0 = sv.x, s1 = sv.y, s2 = sv.z, s3 = sv.w;
        uint2 u0 = hb64[s0 * 32u + l];
        uint2 u1 = hb64[s1 * 32u + l];
        uint2 u2 = hb64[s2 * 32u + l];
        uint2 u3 = hb64[s3 * 32u + l];
        float e0 = asb[s0 * H + ht], e1 = asb[s1 * H + ht];
        float e2 = asb[s2 * H + ht], e3 = asb[s3 * H + ht];
        float p0 = __expf(lrelu(e0 + adn) - m);
        float p1 = __expf(lrelu(e1 + adn) - m);
        float p2 = __expf(lrelu(e2 + adn) - m);
        float p3 = __expf(lrelu(e3 + adn) - m);
        a0 += p0 * bflo(u0.x); a1 += p0 * bfhi(u0.x); a2 += p0 * bflo(u0.y); a3 += p0 * bfhi(u0.y);
        a0 += p1 * bflo(u1.x); a1 += p1 * bfhi(u1.x); a2 += p1 * bflo(u1.y); a3 += p1 * bfhi(u1.y);
        a0 += p2 * bflo(u2.x); a1 += p2 * bfhi(u2.x); a2 += p2 * bflo(u2.y); a3 += p2 * bfhi(u2.y);
        a0 += p3 * bflo(u3.x); a1 += p3 * bfhi(u3.x); a2 += p3 * bflo(u3.y); a3 += p3 * bfhi(u3.y);
        den += p0 + p1 + p2 + p3;
    }
    float inv = 1.f / (den + 1e-16f);
    unsigned c = l * 4;
    float4 bv = *(const float4*)&bias[c];
    float o0 = a0 * inv + bv.x;
    float o1 = a1 * inv + bv.y;
    float o2 = a2 * inv + bv.z;
    float o3 = a3 * inv + bv.w;
    if (RELU) {
        o0 = fmaxf(o0, 0.f); o1 = fmaxf(o1, 0.f);
        o2 = fmaxf(o2, 0.f); o3 = fmaxf(o3, 0.f);
    }
    if (OUTBF) {
        ushort4 o;
        o.x = f2bf(o0); o.y = f2bf(o1); o.z = f2bf(o2); o.w = f2bf(o3);
        *(ushort4*)&((unsigned short*)outv)[(size_t)n * 128 + c] = o;
    } else {
        float4 o; o.x = o0; o.y = o1; o.z = o2; o.w = o3;
        *(float4*)&((float*)outv)[(size_t)n * 128 + c] = o;
    }
}

// ---------------- launch ----------------

extern "C" void kernel_launch(void* const* d_in, const int* in_sizes, int n_in,
                              void* d_out, int out_size, void* d_ws, size_t ws_size,
                              hipStream_t stream) {
    const float* x   = (const float*)d_in[0];
    const int*   ei  = (const int*)d_in[1];
    const float* W1  = (const float*)d_in[2];
    const float* as1 = (const float*)d_in[3];
    const float* ad1 = (const float*)d_in[4];
    const float* b1  = (const float*)d_in[5];
    const float* W2  = (const float*)d_in[6];
    const float* as2 = (const float*)d_in[7];
    const float* ad2 = (const float*)d_in[8];
    const float* b2  = (const float*)d_in[9];
    const float* W3  = (const float*)d_in[10];
    const float* as3 = (const float*)d_in[11];
    const float* ad3 = (const float*)d_in[12];
    const float* b3  = (const float*)d_in[13];

    const int N = in_sizes[0] / 128;
    const int E = in_sizes[1] / 2;
    const int NB = (N + 255) / 256;
    const int PN = (N + NPART - 1) / NPART;

    char* w = (char*)d_ws;
    size_t woff = 0;
    auto alloc = [&](size_t bytes) -> void* {
        void* p = w + woff;
        woff = (woff + bytes + 255) & ~(size_t)255;
        return p;
    };
    int*      deg    = (int*)alloc((size_t)(N + 1) * 4);
    int*      offs   = (int*)alloc((size_t)(N + 1) * 4);
    int*      cursor = (int*)alloc((size_t)(N + 1) * 4);
    int*      bsum   = (int*)alloc((size_t)NB * 4);
    int*      srcs   = (int*)alloc(((size_t)E + 4 * (size_t)N) * 4);
    float*    asb    = (float*)alloc((size_t)(N + 1) * 4 * 4);
    float*    adb    = (float*)alloc((size_t)(N + 1) * 4 * 4);
    unsigned* gmax   = (unsigned*)alloc(16 * 4);
    unsigned short* hb  = (unsigned short*)alloc((size_t)(N + 1) * 128 * 2);
    unsigned short* xb  = (unsigned short*)alloc((size_t)N * 128 * 2);
    unsigned short* Wt1 = (unsigned short*)alloc(128 * 128 * 2);
    unsigned short* Wt2 = (unsigned short*)alloc(128 * 128 * 2);
    unsigned short* Wt3 = (unsigned short*)alloc(128 * 128 * 2);
    float* outf = (float*)d_out;

    // setup: conversions + inits (single kernel)
    int g_setup = (N * 32 + 3 * 16384 + 255) / 256;
    setup<<<g_setup, 256, 0, stream>>>(x, W1, W2, W3, xb, Wt1, Wt2, Wt3, deg, gmax, hb, N);

    // CSR build
    deg_count_part<<<2048, 256, 0, stream>>>(ei, E, N, deg, PN);
    scan_partial<<<NB, 256, 0, stream>>>(deg, N, bsum);
    scan_bsums<<<1, 256, 0, stream>>>(bsum, NB);
    scan_final<<<NB, 256, 0, stream>>>(deg, bsum, N, offs, cursor, srcs);
    scatter_part<<<2048, 256, 0, stream>>>(ei, E, N, cursor, srcs, PN);

    const int gb = (N + 63) / 64;
    const int gl = (N + 31) / 32;
    const int ga = (N + 7) / 8;

    // Layer 1: xb -> hb -> xb (bf16, relu)
    gemm_mfma<<<gb, 256, 0, stream>>>(xb, Wt1, hb, N);
    logits_k<4><<<gl, 256, 0, stream>>>(hb, as1, ad1, asb, adb, gmax + 0, N);
    aggregate7<4, true, true><<<ga, 256, 0, stream>>>(hb, offs, srcs, asb, adb, gmax + 0, b1, xb, N);

    // Layer 2: xb -> hb -> xb (bf16, relu)
    gemm_mfma<<<gb, 256, 0, stream>>>(xb, Wt2, hb, N);
    logits_k<4><<<gl, 256, 0, stream>>>(hb, as2, ad2, asb, adb, gmax + 4, N);
    aggregate7<4, true, true><<<ga, 256, 0, stream>>>(hb, offs, srcs, asb, adb, gmax + 4, b2, xb, N);

    // Layer 3: xb -> hb -> d_out (fp32, H=1, no relu)
    gemm_mfma<<<gb, 256, 0, stream>>>(xb, Wt3, hb, N);
    logits_k<1><<<gl, 256, 0, stream>>>(hb, as3, ad3, asb, adb, gmax + 8, N);
    aggregate7<1, false, false><<<ga, 256, 0, stream>>>(hb, offs, srcs, asb, adb, gmax + 8, b3, outf, N);
}